// Round 4
// baseline (154.462 us; speedup 1.0000x reference)
//
#include <hip/hip_runtime.h>
#include <math.h>

// Problem constants: b=4, f=64, h=w=64, HW=4096
// Inputs: fdm [4,1,128,128], x [4,64,64,64], W_fuse [64,128,3,3], b_fuse [64], gamma [64], beta [64]
// Outputs concatenated: x0 [4,64,64,64] (1048576 f32) then sm [4,1,64,64] (16384 f32)

#define HW 4096
#define NCH 64

typedef __attribute__((ext_vector_type(8))) short short8;
typedef __attribute__((ext_vector_type(4))) float f32x4;

static __device__ __forceinline__ ushort f2bf(float f) {
    unsigned u = __float_as_uint(f);
    unsigned r = (u + 0x7fffu + ((u >> 16) & 1u)) >> 16;   // RNE
    return (ushort)r;
}
static __device__ __forceinline__ float bf2f(ushort h) {
    return __uint_as_float(((unsigned)h) << 16);
}
// order-preserving float <-> uint map for atomicMax
static __device__ __forceinline__ unsigned mapf(float f) {
    unsigned u = __float_as_uint(f);
    return u ^ ((unsigned)((int)u >> 31) | 0x80000000u);
}
static __device__ __forceinline__ float unmapf(unsigned u) {
    unsigned b = (u & 0x80000000u) ? (u ^ 0x80000000u) : ~u;
    return __uint_as_float(b);
}

// ---------------- K1: pool (blocks 0-3)  ||  norm + bf16-prep (blocks 4-259) ----------------
// inb layout: [b][8 grp][sp 4096][16 halves]; grp 0-3 = sm*x ch {0..63}, grp 4-7 = x ch {0..63}.
__global__ __launch_bounds__(256) void k_pnp(
    const float* __restrict__ fdm, const float* __restrict__ x,
    float* __restrict__ pooledOut, float* __restrict__ threOut,
    int* __restrict__ unsel, int* __restrict__ unselN,
    float* __restrict__ gnS1, float* __restrict__ gnS2,
    float* __restrict__ rn, float* __restrict__ smOut, ushort* __restrict__ inb) {
    const int t = threadIdx.x;
    if (blockIdx.x < 4) {
        // ---- pool path ----
        const int b = blockIdx.x;
        __shared__ float pooled[4096];
        __shared__ float red[256];
        __shared__ int cnt;
        const float* fb = fdm + b * 16384;
        float lmax = -1.0f;
#pragma unroll
        for (int it = 0; it < 8; ++it) {
            int id2 = it * 256 + t;
            int i = id2 >> 5;
            int j2 = id2 & 31;
            const float* base = fb + i * 256 + j2 * 4;
            float4 a = *(const float4*)base;
            float4 c = *(const float4*)(base + 128);
            float p0 = fmaxf(fmaxf(a.x, a.y), fmaxf(c.x, c.y));
            float p1 = fmaxf(fmaxf(a.z, a.w), fmaxf(c.z, c.w));
            pooled[i * 64 + j2 * 2]     = p0;
            pooled[i * 64 + j2 * 2 + 1] = p1;
            lmax = fmaxf(lmax, fmaxf(p0, p1));
        }
        red[t] = lmax;
        __syncthreads();
        for (int s = 128; s > 0; s >>= 1) {
            if (t < s) red[t] = fmaxf(red[t], red[t + s]);
            __syncthreads();
        }
        __shared__ float thre_s;
        if (t == 0) {
            thre_s = fminf(0.5f, red[0] / 3.0f);   // exact reference fp32 rounding
            cnt = 0;
            gnS1[b] = 0.0f; gnS2[b] = 0.0f;
        }
        __syncthreads();
        const float th = thre_s;
#pragma unroll
        for (int it = 0; it < 4; ++it) {
            int idx = (it * 256 + t) * 4;
            *(float4*)(pooledOut + b * 4096 + idx) = *(const float4*)(pooled + idx);
        }
        for (int idx = t; idx < 4096; idx += 256) {
            if (!(pooled[idx] >= th)) {
                int pos = atomicAdd(&cnt, 1);
                unsel[b * 4096 + pos] = idx;
            }
        }
        __syncthreads();
        if (t == 0) { unselN[b] = cnt; threOut[b] = th; }
    } else {
        // ---- norm + prep path ----
        __shared__ float s_part[4][64];
        const int n = blockIdx.x - 4;       // 0..255
        const int b = n >> 6;
        const int pbase = (n & 63) * 64;
        const int wv = t >> 6;              // channel group of 16
        const int l = t & 63;               // position within 64-slice
        const int sp = pbase + l;
        const float* xp = x + b * (NCH * HW) + sp;
        float xv[16];
        float ss = 0.f;
#pragma unroll
        for (int i = 0; i < 16; ++i) {
            float a = xp[(wv * 16 + i) * HW];
            xv[i] = a;
            ss += a * a;
        }
        s_part[wv][l] = ss;
        // pack bf16 and write both halves (scale=1 initially; fixup rescales unselected later)
        ushort h[16];
#pragma unroll
        for (int i = 0; i < 16; ++i) h[i] = f2bf(xv[i]);
        size_t dst1 = ((size_t)(b * 8 + wv) * 4096 + sp) * 16;
        size_t dst2 = ((size_t)(b * 8 + 4 + wv) * 4096 + sp) * 16;
        *(uint4*)(inb + dst1)     = *(const uint4*)h;
        *(uint4*)(inb + dst1 + 8) = *(const uint4*)(h + 8);
        *(uint4*)(inb + dst2)     = *(const uint4*)h;
        *(uint4*)(inb + dst2 + 8) = *(const uint4*)(h + 8);
        __syncthreads();
        if (t < 64) {
            float s = s_part[0][l] + s_part[1][l] + s_part[2][l] + s_part[3][l];
            int g = b * HW + pbase + l;
            rn[g] = 1.0f / fmaxf(sqrtf(s), 1e-8f);
            smOut[g] = 1.0f;
        }
    }
}

// ---------------- K2: qgather + score init (blocks 0-3)  ||  weight prep (blocks 4-39) ----------------
__global__ void k_qgw(const float* __restrict__ x, const float* __restrict__ rn,
                      const int* __restrict__ unsel, const int* __restrict__ unselN,
                      float* __restrict__ qmat, unsigned* __restrict__ scores,
                      const float* __restrict__ W, ushort* __restrict__ wbh, ushort* __restrict__ wbl) {
    const int t = threadIdx.x;
    if (blockIdx.x < 4) {
        const int b = blockIdx.x;
        const int nu = unselN[b];
        for (int qi = t; qi < nu; qi += 256) scores[b * 4096 + qi] = 0u;
        for (int idx = t; idx < nu * 64; idx += 256) {
            int qi = idx >> 6;
            int c = idx & 63;
            int q = unsel[b * 4096 + qi];
            float rq = rn[b * 4096 + q];
            qmat[((size_t)(b * 4096 + qi)) * 64 + c] = x[b * (NCH * HW) + c * HW + q] * rq;
        }
    } else {
        const int u = (blockIdx.x - 4) * 256 + t;   // 0..9215 = tap*1024 + oc*16 + g
        const int tap = u >> 10;
        const int rem = u & 1023;
        const int oc = rem >> 4;
        const int g = rem & 15;
        ushort hh[8], ll[8];
#pragma unroll
        for (int j = 0; j < 8; ++j) {
            int ic = g * 8 + j;
            float v = W[(oc * 128 + ic) * 9 + tap];
            ushort hb = f2bf(v);
            hh[j] = hb;
            ll[j] = f2bf(v - bf2f(hb));
        }
        *(uint4*)(wbh + (size_t)u * 8) = *(const uint4*)hh;
        *(uint4*)(wbl + (size_t)u * 8) = *(const uint4*)ll;
    }
}

// ---------------- K3: score — for each unselected q, max over selected p of cos(x_p, x_q) ----------------
// grid (64 pblk, 4 b), 256 threads. Thread owns p = pblk*64 + (t&63), x[:,p] cached in 64 VGPRs.
// 4 q-slots across the 4 waves; q vectors read as wave-uniform broadcast float4 from qmat (rq prefolded).
__global__ __launch_bounds__(256) void k_score(
    const float* __restrict__ x, const float* __restrict__ rn,
    const float* __restrict__ pooledM, const float* __restrict__ threArr,
    const int* __restrict__ unselN, const float* __restrict__ qmat,
    unsigned* __restrict__ scores) {
    const int pblk = blockIdx.x;
    const int b = blockIdx.y;
    const int t = threadIdx.x;
    const int lane = t & 63;
    const int qs = t >> 6;
    const int nu = unselN[b];
    if (nu == 0) return;
    const int p = pblk * 64 + lane;
    const float th = threArr[b];
    const bool maskp = pooledM[b * 4096 + p] >= th;
    const float rp = rn[b * 4096 + p];
    float xr[64];
    const float* xb = x + b * (NCH * HW) + p;
#pragma unroll
    for (int c = 0; c < 64; ++c) xr[c] = xb[c * HW];
    for (int qi = qs; qi < nu; qi += 4) {
        const float4* qv = (const float4*)(qmat + ((size_t)(b * 4096 + qi)) * 64);
        float d0 = 0.f, d1 = 0.f, d2 = 0.f, d3 = 0.f;
#pragma unroll
        for (int c4 = 0; c4 < 16; ++c4) {
            float4 v = qv[c4];
            d0 += xr[c4 * 4 + 0] * v.x;
            d1 += xr[c4 * 4 + 1] * v.y;
            d2 += xr[c4 * 4 + 2] * v.z;
            d3 += xr[c4 * 4 + 3] * v.w;
        }
        float cosv = ((d0 + d1) + (d2 + d3)) * rp;
        float sc = maskp ? cosv : -INFINITY;
#pragma unroll
        for (int off = 32; off > 0; off >>= 1) sc = fmaxf(sc, __shfl_xor(sc, off));
        if (lane == 0) atomicMax(scores + b * 4096 + qi, mapf(sc));
    }
}

// ---------------- K4: fixup — finalize sm for unselected q, rescale their inb entries ----------------
__global__ void k_fixup(const float* __restrict__ x, const int* __restrict__ unsel,
                        const int* __restrict__ unselN, const unsigned* __restrict__ scores,
                        float* __restrict__ smOut, ushort* __restrict__ inb) {
    const int b = blockIdx.x;
    const int t = threadIdx.x;
    const int nu = unselN[b];
    __shared__ float s_sm[4096];
    for (int qi = t; qi < nu; qi += 256) {
        float sm = unmapf(scores[b * 4096 + qi]) * 0.5f + 0.5f;
        s_sm[qi] = sm;
        smOut[b * 4096 + unsel[b * 4096 + qi]] = sm;
    }
    __syncthreads();
    for (int idx = t; idx < nu * 64; idx += 256) {
        int qi = idx >> 6;
        int c = idx & 63;
        int q = unsel[b * 4096 + qi];
        float v = x[b * (NCH * HW) + c * HW + q] * s_sm[qi];
        inb[(((size_t)(b * 8 + (c >> 4)) * 4096) + q) * 16 + (c & 15)] = f2bf(v);
    }
}

// ---------------- K5: MFMA implicit-GEMM conv 3x3 (128->64) + bias + GN partials ----------------
// grid (16 rowblk, 4 ocblk, 4 b), block 256 = 4 waves (one per output row).
// Wave computes 16 oc x 64 w via 4 C-tiles of 16x16. A = weights (m=oc), B = input (n=w).
__global__ __launch_bounds__(256) void k_conv_mfma(
    const ushort* __restrict__ inb, const ushort* __restrict__ wbh, const ushort* __restrict__ wbl,
    const float* __restrict__ bfuse, float* __restrict__ y,
    float* __restrict__ gnS1, float* __restrict__ gnS2) {
    const int rowblk = blockIdx.x;
    const int ocblk = blockIdx.y;
    const int b = blockIdx.z;
    const int t = threadIdx.x;
    const int lane = t & 63;
    const int wave = t >> 6;
    const int li = lane & 15;
    const int quad = lane >> 4;
    const int h0 = rowblk * 4;
    const int oc0 = ocblk * 16;

    __shared__ __align__(16) ushort s_in[6 * 66 * 40];   // [r][c][32ic pad40] halves
    __shared__ __align__(16) ushort s_wh[9 * 16 * 40];   // [tap][oc][32ic pad40]
    __shared__ __align__(16) ushort s_wl[9 * 16 * 40];
    __shared__ float red1[256];
    __shared__ float red2[256];

    f32x4 acc[4];
#pragma unroll
    for (int j = 0; j < 4; ++j) acc[j] = (f32x4){0.f, 0.f, 0.f, 0.f};

    for (int chunk = 0; chunk < 4; ++chunk) {
        __syncthreads();
        // stage input slab: rows h0-1..h0+4, cols -1..64, 32 ic (4 x 16B parts per cell)
        // inb layout: [b][8 grp][sp][16 halves]; chunk c covers grps {2c, 2c+1}
        for (int idx = t; idx < 1584; idx += 256) {
            int part = idx & 3;
            int cell = idx >> 2;
            int r = cell / 66;
            int c = cell - r * 66;
            int h = h0 + r - 1;
            int w = c - 1;
            uint4 v = make_uint4(0u, 0u, 0u, 0u);
            if ((unsigned)h < 64u && (unsigned)w < 64u) {
                int grp = 2 * chunk + (part >> 1);
                int sub = part & 1;
                v = *(const uint4*)(inb + (((size_t)(b * 8 + grp) * 4096 + h * 64 + w) * 16 + sub * 8));
            }
            *(uint4*)(s_in + (size_t)cell * 40 + part * 8) = v;
        }
        // stage weights: {hi,lo} x 9 taps x 16 oc x 4 parts
        const int ic0 = chunk * 32;
        for (int idx = t; idx < 1152; idx += 256) {
            int part = idx & 3;
            int uu = idx >> 2;              // hl*144 + tap*16 + o
            int hl = uu / 144;
            int rem = uu - hl * 144;
            int tap = rem >> 4;
            int o = rem & 15;
            const ushort* src = (hl ? wbl : wbh) + ((size_t)(tap * 64 + oc0 + o) * 128 + ic0 + part * 8);
            uint4 v = *(const uint4*)src;
            ushort* dst = (hl ? s_wl : s_wh) + ((size_t)(tap * 16 + o) * 40 + part * 8);
            *(uint4*)dst = v;
        }
        __syncthreads();
#pragma unroll
        for (int kh = 0; kh < 3; ++kh) {
            const int r = wave + kh;
#pragma unroll
            for (int kw = 0; kw < 3; ++kw) {
                const int tap = kh * 3 + kw;
                short8 ah = *(const short8*)(s_wh + (size_t)(tap * 16 + li) * 40 + quad * 8);
                short8 al = *(const short8*)(s_wl + (size_t)(tap * 16 + li) * 40 + quad * 8);
#pragma unroll
                for (int j = 0; j < 4; ++j) {
                    int c = j * 16 + li + kw;
                    short8 bv = *(const short8*)(s_in + ((size_t)(r * 66 + c) * 40 + quad * 8));
                    acc[j] = __builtin_amdgcn_mfma_f32_16x16x32_bf16(ah, bv, acc[j], 0, 0, 0);
                    acc[j] = __builtin_amdgcn_mfma_f32_16x16x32_bf16(al, bv, acc[j], 0, 0, 0);
                }
            }
        }
    }
    // epilogue: bias, store (coalesced: col=lane&15 is w), GN partial sums
    float bias[4];
#pragma unroll
    for (int reg = 0; reg < 4; ++reg) bias[reg] = bfuse[oc0 + quad * 4 + reg];
    float s1 = 0.f, s2 = 0.f;
    const int hrow = h0 + wave;
#pragma unroll
    for (int j = 0; j < 4; ++j) {
#pragma unroll
        for (int reg = 0; reg < 4; ++reg) {
            float v = acc[j][reg] + bias[reg];
            y[((size_t)(b * 64 + oc0 + quad * 4 + reg)) * HW + hrow * 64 + j * 16 + li] = v;
            s1 += v; s2 += v * v;
        }
    }
    red1[t] = s1; red2[t] = s2;
    __syncthreads();
    for (int s = 128; s > 0; s >>= 1) {
        if (t < s) { red1[t] += red1[t + s]; red2[t] += red2[t + s]; }
        __syncthreads();
    }
    if (t == 0) {
        atomicAdd(&gnS1[b], red1[0]);
        atomicAdd(&gnS2[b], red2[0]);
    }
}

// ---------------- K6: GroupNorm(1 group) + affine + ReLU, in-place on out ----------------
__global__ void k_gn(float* __restrict__ out, const float* __restrict__ gnS1, const float* __restrict__ gnS2,
                     const float* __restrict__ gamma, const float* __restrict__ beta) {
    const int e = (blockIdx.x * 256 + threadIdx.x) * 4;
    const int b = e >> 18;
    const int c = (e >> 12) & 63;
    const float inv = 1.0f / 262144.0f;
    float mu = gnS1[b] * inv;
    float var = gnS2[b] * inv - mu * mu;
    float rs = rsqrtf(var + 1e-5f);
    float scale = rs * gamma[c];
    float shift = beta[c] - mu * scale;
    float4 v = *(const float4*)(out + e);
    float4 o;
    o.x = fmaxf(v.x * scale + shift, 0.0f);
    o.y = fmaxf(v.y * scale + shift, 0.0f);
    o.z = fmaxf(v.z * scale + shift, 0.0f);
    o.w = fmaxf(v.w * scale + shift, 0.0f);
    *(float4*)(out + e) = o;
}

extern "C" void kernel_launch(void* const* d_in, const int* in_sizes, int n_in,
                              void* d_out, int out_size, void* d_ws, size_t ws_size,
                              hipStream_t stream) {
    const float* fdm   = (const float*)d_in[0];
    const float* x     = (const float*)d_in[1];
    const float* Wf    = (const float*)d_in[2];
    const float* bfuse = (const float*)d_in[3];
    const float* gamma = (const float*)d_in[4];
    const float* beta  = (const float*)d_in[5];
    float* out = (float*)d_out;
    float* ws  = (float*)d_ws;

    // workspace layout (float offsets, all 16B-aligned)
    float*    rn      = ws;                         // 16384
    float*    pooledM = rn + 16384;                 // 16384
    int*      unsel   = (int*)(pooledM + 16384);    // 16384
    unsigned* scores  = (unsigned*)(unsel + 16384); // 16384
    float*    qmat    = (float*)(scores + 16384);   // 1048576
    float*    thre    = qmat + 1048576;             // 4
    int*      unselN  = (int*)(thre + 4);           // 4
    float*    gnS1    = (float*)(unselN + 4);       // 4
    float*    gnS2    = gnS1 + 4;                   // 4
    ushort*   wbh     = (ushort*)(gnS2 + 4);        // 73728 halves
    ushort*   wbl     = wbh + 73728;                // 73728 halves
    ushort*   inb     = wbl + 73728;                // 4194304 halves (8 MB)

    float* yout  = out;                             // conv output in out[0..1M), GN in-place
    float* smOut = out + 1048576;                   // second output

    k_pnp<<<dim3(260), dim3(256), 0, stream>>>(fdm, x, pooledM, thre, unsel, unselN,
                                               gnS1, gnS2, rn, smOut, inb);
    k_qgw<<<dim3(40), dim3(256), 0, stream>>>(x, rn, unsel, unselN, qmat, scores, Wf, wbh, wbl);
    k_score<<<dim3(64, 4), dim3(256), 0, stream>>>(x, rn, pooledM, thre, unselN, qmat, scores);
    k_fixup<<<dim3(4), dim3(256), 0, stream>>>(x, unsel, unselN, scores, smOut, inb);
    k_conv_mfma<<<dim3(16, 4, 4), dim3(256), 0, stream>>>(inb, wbh, wbl, bfuse, yout, gnS1, gnS2);
    k_gn<<<dim3(1024), dim3(256), 0, stream>>>(yout, gnS1, gnS2, gamma, beta);
}

// Round 5
// 152.823 us; speedup vs baseline: 1.0107x; 1.0107x over previous
//
#include <hip/hip_runtime.h>
#include <math.h>

// Problem constants: b=4, f=64, h=w=64, HW=4096
// Inputs: fdm [4,1,128,128], x [4,64,64,64], W_fuse [64,128,3,3], b_fuse [64], gamma [64], beta [64]
// Outputs concatenated: x0 [4,64,64,64] (1048576 f32) then sm [4,1,64,64] (16384 f32)

#define HW 4096
#define NCH 64

typedef __attribute__((ext_vector_type(8))) short short8;
typedef __attribute__((ext_vector_type(4))) float f32x4;

static __device__ __forceinline__ ushort f2bf(float f) {
    unsigned u = __float_as_uint(f);
    unsigned r = (u + 0x7fffu + ((u >> 16) & 1u)) >> 16;   // RNE
    return (ushort)r;
}
static __device__ __forceinline__ float bf2f(ushort h) {
    return __uint_as_float(((unsigned)h) << 16);
}
// order-preserving float <-> uint map for atomicMax
static __device__ __forceinline__ unsigned mapf(float f) {
    unsigned u = __float_as_uint(f);
    return u ^ ((unsigned)((int)u >> 31) | 0x80000000u);
}
static __device__ __forceinline__ float unmapf(unsigned u) {
    unsigned b = (u & 0x80000000u) ? (u ^ 0x80000000u) : ~u;
    return __uint_as_float(b);
}

// ---------------- K1: pool (blocks 0-3)  ||  norm + bf16-prep (blocks 4-259) ----------------
// inb layout: [b][8 grp][sp 4096][16 halves]; grp 0-3 = sm*x ch {0..63}, grp 4-7 = x ch {0..63}.
__global__ __launch_bounds__(256) void k_pnp(
    const float* __restrict__ fdm, const float* __restrict__ x,
    float* __restrict__ pooledOut, float* __restrict__ threOut,
    int* __restrict__ unsel, int* __restrict__ unselN,
    float* __restrict__ gnS1, float* __restrict__ gnS2,
    float* __restrict__ rn, float* __restrict__ smOut, ushort* __restrict__ inb) {
    const int t = threadIdx.x;
    if (blockIdx.x < 4) {
        // ---- pool path ----
        const int b = blockIdx.x;
        __shared__ float pooled[4096];
        __shared__ float red[256];
        __shared__ int cnt;
        const float* fb = fdm + b * 16384;
        float lmax = -1.0f;
#pragma unroll
        for (int it = 0; it < 8; ++it) {
            int id2 = it * 256 + t;
            int i = id2 >> 5;
            int j2 = id2 & 31;
            const float* base = fb + i * 256 + j2 * 4;
            float4 a = *(const float4*)base;
            float4 c = *(const float4*)(base + 128);
            float p0 = fmaxf(fmaxf(a.x, a.y), fmaxf(c.x, c.y));
            float p1 = fmaxf(fmaxf(a.z, a.w), fmaxf(c.z, c.w));
            pooled[i * 64 + j2 * 2]     = p0;
            pooled[i * 64 + j2 * 2 + 1] = p1;
            lmax = fmaxf(lmax, fmaxf(p0, p1));
        }
        red[t] = lmax;
        __syncthreads();
        for (int s = 128; s > 0; s >>= 1) {
            if (t < s) red[t] = fmaxf(red[t], red[t + s]);
            __syncthreads();
        }
        __shared__ float thre_s;
        if (t == 0) {
            thre_s = fminf(0.5f, red[0] / 3.0f);   // exact reference fp32 rounding
            cnt = 0;
            gnS1[b] = 0.0f; gnS2[b] = 0.0f;
        }
        __syncthreads();
        const float th = thre_s;
#pragma unroll
        for (int it = 0; it < 4; ++it) {
            int idx = (it * 256 + t) * 4;
            *(float4*)(pooledOut + b * 4096 + idx) = *(const float4*)(pooled + idx);
        }
        for (int idx = t; idx < 4096; idx += 256) {
            if (!(pooled[idx] >= th)) {
                int pos = atomicAdd(&cnt, 1);
                unsel[b * 4096 + pos] = idx;
            }
        }
        __syncthreads();
        if (t == 0) { unselN[b] = cnt; threOut[b] = th; }
    } else {
        // ---- norm + prep path ----
        __shared__ float s_part[4][64];
        const int n = blockIdx.x - 4;       // 0..255
        const int b = n >> 6;
        const int pbase = (n & 63) * 64;
        const int wv = t >> 6;              // channel group of 16
        const int l = t & 63;               // position within 64-slice
        const int sp = pbase + l;
        const float* xp = x + b * (NCH * HW) + sp;
        float xv[16];
        float ss = 0.f;
#pragma unroll
        for (int i = 0; i < 16; ++i) {
            float a = xp[(wv * 16 + i) * HW];
            xv[i] = a;
            ss += a * a;
        }
        s_part[wv][l] = ss;
        // pack bf16 and write both halves (scale=1 initially; fixup rescales unselected later)
        ushort h[16];
#pragma unroll
        for (int i = 0; i < 16; ++i) h[i] = f2bf(xv[i]);
        size_t dst1 = ((size_t)(b * 8 + wv) * 4096 + sp) * 16;
        size_t dst2 = ((size_t)(b * 8 + 4 + wv) * 4096 + sp) * 16;
        *(uint4*)(inb + dst1)     = *(const uint4*)h;
        *(uint4*)(inb + dst1 + 8) = *(const uint4*)(h + 8);
        *(uint4*)(inb + dst2)     = *(const uint4*)h;
        *(uint4*)(inb + dst2 + 8) = *(const uint4*)(h + 8);
        __syncthreads();
        if (t < 64) {
            float s = s_part[0][l] + s_part[1][l] + s_part[2][l] + s_part[3][l];
            int g = b * HW + pbase + l;
            rn[g] = 1.0f / fmaxf(sqrtf(s), 1e-8f);
            smOut[g] = 1.0f;
        }
    }
}

// ---------------- K2: qgather + score init (blocks 0-3)  ||  weight prep (blocks 4-39) ----------------
__global__ void k_qgw(const float* __restrict__ x, const float* __restrict__ rn,
                      const int* __restrict__ unsel, const int* __restrict__ unselN,
                      float* __restrict__ qmat, unsigned* __restrict__ scores,
                      const float* __restrict__ W, ushort* __restrict__ wbh, ushort* __restrict__ wbl) {
    const int t = threadIdx.x;
    if (blockIdx.x < 4) {
        const int b = blockIdx.x;
        const int nu = unselN[b];
        for (int qi = t; qi < nu; qi += 256) scores[b * 4096 + qi] = 0u;
        for (int idx = t; idx < nu * 64; idx += 256) {
            int qi = idx >> 6;
            int c = idx & 63;
            int q = unsel[b * 4096 + qi];
            float rq = rn[b * 4096 + q];
            qmat[((size_t)(b * 4096 + qi)) * 64 + c] = x[b * (NCH * HW) + c * HW + q] * rq;
        }
    } else {
        const int u = (blockIdx.x - 4) * 256 + t;   // 0..9215 = tap*1024 + oc*16 + g
        const int tap = u >> 10;
        const int rem = u & 1023;
        const int oc = rem >> 4;
        const int g = rem & 15;
        ushort hh[8], ll[8];
#pragma unroll
        for (int j = 0; j < 8; ++j) {
            int ic = g * 8 + j;
            float v = W[(oc * 128 + ic) * 9 + tap];
            ushort hb = f2bf(v);
            hh[j] = hb;
            ll[j] = f2bf(v - bf2f(hb));
        }
        *(uint4*)(wbh + (size_t)u * 8) = *(const uint4*)hh;
        *(uint4*)(wbl + (size_t)u * 8) = *(const uint4*)ll;
    }
}

// ---------------- K3: score — for each unselected q, max over selected p of cos(x_p, x_q) ----------------
// grid (64 pblk, 4 b), 256 threads. Thread owns p = pblk*64 + (t&63); x[:,p] cached in 16 float4 regs.
// __launch_bounds__(256, 1): 1 block/CU -> full VGPR budget, prevents the R4 spill (VGPR was 48 < 64 needed).
__global__ __launch_bounds__(256, 1) void k_score(
    const float* __restrict__ x, const float* __restrict__ rn,
    const float* __restrict__ pooledM, const float* __restrict__ threArr,
    const int* __restrict__ unselN, const float* __restrict__ qmat,
    unsigned* __restrict__ scores) {
    const int pblk = blockIdx.x;
    const int b = blockIdx.y;
    const int t = threadIdx.x;
    const int lane = t & 63;
    const int qs = t >> 6;
    const int nu = unselN[b];
    if (nu == 0) return;
    const int p = pblk * 64 + lane;
    const float th = threArr[b];
    const bool maskp = pooledM[b * 4096 + p] >= th;
    const float rp = rn[b * 4096 + p];
    float4 xr[16];
    const float* xb = x + b * (NCH * HW) + p;
#pragma unroll
    for (int c4 = 0; c4 < 16; ++c4) {
        xr[c4].x = xb[(c4 * 4 + 0) * HW];
        xr[c4].y = xb[(c4 * 4 + 1) * HW];
        xr[c4].z = xb[(c4 * 4 + 2) * HW];
        xr[c4].w = xb[(c4 * 4 + 3) * HW];
    }
    unsigned* scb = scores + b * 4096;
    const float* qb = qmat + ((size_t)b * 4096) * 64;
    for (int qi = qs; qi < nu; qi += 4) {
        const float4* qv = (const float4*)(qb + (size_t)qi * 64);
        float d0 = 0.f, d1 = 0.f, d2 = 0.f, d3 = 0.f;
#pragma unroll
        for (int c4 = 0; c4 < 16; ++c4) {
            float4 v = qv[c4];
            d0 += xr[c4].x * v.x;
            d1 += xr[c4].y * v.y;
            d2 += xr[c4].z * v.z;
            d3 += xr[c4].w * v.w;
        }
        float cosv = ((d0 + d1) + (d2 + d3)) * rp;
        float sc = maskp ? cosv : -INFINITY;
#pragma unroll
        for (int off = 32; off > 0; off >>= 1) sc = fmaxf(sc, __shfl_xor(sc, off));
        if (lane == 0) atomicMax(scb + qi, mapf(sc));
    }
}

// ---------------- K4: fixup — finalize sm for unselected q, rescale their inb entries ----------------
__global__ void k_fixup(const float* __restrict__ x, const int* __restrict__ unsel,
                        const int* __restrict__ unselN, const unsigned* __restrict__ scores,
                        float* __restrict__ smOut, ushort* __restrict__ inb) {
    const int b = blockIdx.x;
    const int t = threadIdx.x;
    const int nu = unselN[b];
    __shared__ float s_sm[4096];
    for (int qi = t; qi < nu; qi += 256) {
        float sm = unmapf(scores[b * 4096 + qi]) * 0.5f + 0.5f;
        s_sm[qi] = sm;
        smOut[b * 4096 + unsel[b * 4096 + qi]] = sm;
    }
    __syncthreads();
    for (int idx = t; idx < nu * 64; idx += 256) {
        int qi = idx >> 6;
        int c = idx & 63;
        int q = unsel[b * 4096 + qi];
        float v = x[b * (NCH * HW) + c * HW + q] * s_sm[qi];
        inb[(((size_t)(b * 8 + (c >> 4)) * 4096) + q) * 16 + (c & 15)] = f2bf(v);
    }
}

// ---------------- K5: MFMA implicit-GEMM conv 3x3 (128->64) + bias + GN partials ----------------
// grid (16 rowblk, 4 ocblk, 4 b), block 256 = 4 waves (one per output row).
// Wave computes 16 oc x 64 w via 4 C-tiles of 16x16. A = weights (m=oc), B = input (n=w).
__global__ __launch_bounds__(256) void k_conv_mfma(
    const ushort* __restrict__ inb, const ushort* __restrict__ wbh, const ushort* __restrict__ wbl,
    const float* __restrict__ bfuse, float* __restrict__ y,
    float* __restrict__ gnS1, float* __restrict__ gnS2) {
    const int rowblk = blockIdx.x;
    const int ocblk = blockIdx.y;
    const int b = blockIdx.z;
    const int t = threadIdx.x;
    const int lane = t & 63;
    const int wave = t >> 6;
    const int li = lane & 15;
    const int quad = lane >> 4;
    const int h0 = rowblk * 4;
    const int oc0 = ocblk * 16;

    __shared__ __align__(16) ushort s_in[6 * 66 * 40];   // [r][c][32ic pad40] halves
    __shared__ __align__(16) ushort s_wh[9 * 16 * 40];   // [tap][oc][32ic pad40]
    __shared__ __align__(16) ushort s_wl[9 * 16 * 40];
    __shared__ float red1[256];
    __shared__ float red2[256];

    f32x4 acc[4];
#pragma unroll
    for (int j = 0; j < 4; ++j) acc[j] = (f32x4){0.f, 0.f, 0.f, 0.f};

    for (int chunk = 0; chunk < 4; ++chunk) {
        __syncthreads();
        // stage input slab: rows h0-1..h0+4, cols -1..64, 32 ic (4 x 16B parts per cell)
        // inb layout: [b][8 grp][sp][16 halves]; chunk c covers grps {2c, 2c+1}
        for (int idx = t; idx < 1584; idx += 256) {
            int part = idx & 3;
            int cell = idx >> 2;
            int r = cell / 66;
            int c = cell - r * 66;
            int h = h0 + r - 1;
            int w = c - 1;
            uint4 v = make_uint4(0u, 0u, 0u, 0u);
            if ((unsigned)h < 64u && (unsigned)w < 64u) {
                int grp = 2 * chunk + (part >> 1);
                int sub = part & 1;
                v = *(const uint4*)(inb + (((size_t)(b * 8 + grp) * 4096 + h * 64 + w) * 16 + sub * 8));
            }
            *(uint4*)(s_in + (size_t)cell * 40 + part * 8) = v;
        }
        // stage weights: {hi,lo} x 9 taps x 16 oc x 4 parts
        const int ic0 = chunk * 32;
        for (int idx = t; idx < 1152; idx += 256) {
            int part = idx & 3;
            int uu = idx >> 2;              // hl*144 + tap*16 + o
            int hl = uu / 144;
            int rem = uu - hl * 144;
            int tap = rem >> 4;
            int o = rem & 15;
            const ushort* src = (hl ? wbl : wbh) + ((size_t)(tap * 64 + oc0 + o) * 128 + ic0 + part * 8);
            uint4 v = *(const uint4*)src;
            ushort* dst = (hl ? s_wl : s_wh) + ((size_t)(tap * 16 + o) * 40 + part * 8);
            *(uint4*)dst = v;
        }
        __syncthreads();
#pragma unroll
        for (int kh = 0; kh < 3; ++kh) {
            const int r = wave + kh;
#pragma unroll
            for (int kw = 0; kw < 3; ++kw) {
                const int tap = kh * 3 + kw;
                short8 ah = *(const short8*)(s_wh + (size_t)(tap * 16 + li) * 40 + quad * 8);
                short8 al = *(const short8*)(s_wl + (size_t)(tap * 16 + li) * 40 + quad * 8);
#pragma unroll
                for (int j = 0; j < 4; ++j) {
                    int c = j * 16 + li + kw;
                    short8 bv = *(const short8*)(s_in + ((size_t)(r * 66 + c) * 40 + quad * 8));
                    acc[j] = __builtin_amdgcn_mfma_f32_16x16x32_bf16(ah, bv, acc[j], 0, 0, 0);
                    acc[j] = __builtin_amdgcn_mfma_f32_16x16x32_bf16(al, bv, acc[j], 0, 0, 0);
                }
            }
        }
    }
    // epilogue: bias, store (coalesced: col=lane&15 is w), GN partial sums
    float bias[4];
#pragma unroll
    for (int reg = 0; reg < 4; ++reg) bias[reg] = bfuse[oc0 + quad * 4 + reg];
    float s1 = 0.f, s2 = 0.f;
    const int hrow = h0 + wave;
#pragma unroll
    for (int j = 0; j < 4; ++j) {
#pragma unroll
        for (int reg = 0; reg < 4; ++reg) {
            float v = acc[j][reg] + bias[reg];
            y[((size_t)(b * 64 + oc0 + quad * 4 + reg)) * HW + hrow * 64 + j * 16 + li] = v;
            s1 += v; s2 += v * v;
        }
    }
    red1[t] = s1; red2[t] = s2;
    __syncthreads();
    for (int s = 128; s > 0; s >>= 1) {
        if (t < s) { red1[t] += red1[t + s]; red2[t] += red2[t + s]; }
        __syncthreads();
    }
    if (t == 0) {
        atomicAdd(&gnS1[b], red1[0]);
        atomicAdd(&gnS2[b], red2[0]);
    }
}

// ---------------- K6: GroupNorm(1 group) + affine + ReLU, in-place on out ----------------
__global__ void k_gn(float* __restrict__ out, const float* __restrict__ gnS1, const float* __restrict__ gnS2,
                     const float* __restrict__ gamma, const float* __restrict__ beta) {
    const int e = (blockIdx.x * 256 + threadIdx.x) * 4;
    const int b = e >> 18;
    const int c = (e >> 12) & 63;
    const float inv = 1.0f / 262144.0f;
    float mu = gnS1[b] * inv;
    float var = gnS2[b] * inv - mu * mu;
    float rs = rsqrtf(var + 1e-5f);
    float scale = rs * gamma[c];
    float shift = beta[c] - mu * scale;
    float4 v = *(const float4*)(out + e);
    float4 o;
    o.x = fmaxf(v.x * scale + shift, 0.0f);
    o.y = fmaxf(v.y * scale + shift, 0.0f);
    o.z = fmaxf(v.z * scale + shift, 0.0f);
    o.w = fmaxf(v.w * scale + shift, 0.0f);
    *(float4*)(out + e) = o;
}

extern "C" void kernel_launch(void* const* d_in, const int* in_sizes, int n_in,
                              void* d_out, int out_size, void* d_ws, size_t ws_size,
                              hipStream_t stream) {
    const float* fdm   = (const float*)d_in[0];
    const float* x     = (const float*)d_in[1];
    const float* Wf    = (const float*)d_in[2];
    const float* bfuse = (const float*)d_in[3];
    const float* gamma = (const float*)d_in[4];
    const float* beta  = (const float*)d_in[5];
    float* out = (float*)d_out;
    float* ws  = (float*)d_ws;

    // workspace layout (float offsets, all 16B-aligned)
    float*    rn      = ws;                         // 16384
    float*    pooledM = rn + 16384;                 // 16384
    int*      unsel   = (int*)(pooledM + 16384);    // 16384
    unsigned* scores  = (unsigned*)(unsel + 16384); // 16384
    float*    qmat    = (float*)(scores + 16384);   // 1048576
    float*    thre    = qmat + 1048576;             // 4
    int*      unselN  = (int*)(thre + 4);           // 4
    float*    gnS1    = (float*)(unselN + 4);       // 4
    float*    gnS2    = gnS1 + 4;                   // 4
    ushort*   wbh     = (ushort*)(gnS2 + 4);        // 73728 halves
    ushort*   wbl     = wbh + 73728;                // 73728 halves
    ushort*   inb     = wbl + 73728;                // 4194304 halves (8 MB)

    float* yout  = out;                             // conv output in out[0..1M), GN in-place
    float* smOut = out + 1048576;                   // second output

    k_pnp<<<dim3(260), dim3(256), 0, stream>>>(fdm, x, pooledM, thre, unsel, unselN,
                                               gnS1, gnS2, rn, smOut, inb);
    k_qgw<<<dim3(40), dim3(256), 0, stream>>>(x, rn, unsel, unselN, qmat, scores, Wf, wbh, wbl);
    k_score<<<dim3(64, 4), dim3(256), 0, stream>>>(x, rn, pooledM, thre, unselN, qmat, scores);
    k_fixup<<<dim3(4), dim3(256), 0, stream>>>(x, unsel, unselN, scores, smOut, inb);
    k_conv_mfma<<<dim3(16, 4, 4), dim3(256), 0, stream>>>(inb, wbh, wbl, bfuse, yout, gnS1, gnS2);
    k_gn<<<dim3(1024), dim3(256), 0, stream>>>(yout, gnS1, gnS2, gamma, beta);
}

// Round 6
// 120.788 us; speedup vs baseline: 1.2788x; 1.2652x over previous
//
#include <hip/hip_runtime.h>
#include <math.h>

// Problem constants: b=4, f=64, h=w=64, HW=4096
// Inputs: fdm [4,1,128,128], x [4,64,64,64], W_fuse [64,128,3,3], b_fuse [64], gamma [64], beta [64]
// Outputs concatenated: x0 [4,64,64,64] (1048576 f32) then sm [4,1,64,64] (16384 f32)

#define HW 4096
#define NCH 64

typedef __attribute__((ext_vector_type(8))) short short8;
typedef __attribute__((ext_vector_type(4))) float f32x4;

static __device__ __forceinline__ ushort f2bf(float f) {
    unsigned u = __float_as_uint(f);
    unsigned r = (u + 0x7fffu + ((u >> 16) & 1u)) >> 16;   // RNE
    return (ushort)r;
}
static __device__ __forceinline__ float bf2f(ushort h) {
    return __uint_as_float(((unsigned)h) << 16);
}
// order-preserving float <-> uint map for atomicMax
static __device__ __forceinline__ unsigned mapf(float f) {
    unsigned u = __float_as_uint(f);
    return u ^ ((unsigned)((int)u >> 31) | 0x80000000u);
}
static __device__ __forceinline__ float unmapf(unsigned u) {
    unsigned b = (u & 0x80000000u) ? (u ^ 0x80000000u) : ~u;
    return __uint_as_float(b);
}

// ---------------- K1: pool (blocks 0-3)  ||  norm + bf16-prep (blocks 4-259) ----------------
// inb layout: [b][8 grp][sp 4096][16 halves]; grp 0-3 = sm*x ch {0..63}, grp 4-7 = x ch {0..63}.
__global__ __launch_bounds__(256) void k_pnp(
    const float* __restrict__ fdm, const float* __restrict__ x,
    float* __restrict__ pooledOut, float* __restrict__ threOut,
    int* __restrict__ unsel, int* __restrict__ unselN,
    float* __restrict__ gnS1, float* __restrict__ gnS2,
    float* __restrict__ rn, float* __restrict__ smOut, ushort* __restrict__ inb) {
    const int t = threadIdx.x;
    if (blockIdx.x < 4) {
        // ---- pool path ----
        const int b = blockIdx.x;
        __shared__ float pooled[4096];
        __shared__ float red[256];
        __shared__ int cnt;
        const float* fb = fdm + b * 16384;
        float lmax = -1.0f;
#pragma unroll
        for (int it = 0; it < 8; ++it) {
            int id2 = it * 256 + t;
            int i = id2 >> 5;
            int j2 = id2 & 31;
            const float* base = fb + i * 256 + j2 * 4;
            float4 a = *(const float4*)base;
            float4 c = *(const float4*)(base + 128);
            float p0 = fmaxf(fmaxf(a.x, a.y), fmaxf(c.x, c.y));
            float p1 = fmaxf(fmaxf(a.z, a.w), fmaxf(c.z, c.w));
            pooled[i * 64 + j2 * 2]     = p0;
            pooled[i * 64 + j2 * 2 + 1] = p1;
            lmax = fmaxf(lmax, fmaxf(p0, p1));
        }
        red[t] = lmax;
        __syncthreads();
        for (int s = 128; s > 0; s >>= 1) {
            if (t < s) red[t] = fmaxf(red[t], red[t + s]);
            __syncthreads();
        }
        __shared__ float thre_s;
        if (t == 0) {
            thre_s = fminf(0.5f, red[0] / 3.0f);   // exact reference fp32 rounding
            cnt = 0;
            gnS1[b] = 0.0f; gnS2[b] = 0.0f;
        }
        __syncthreads();
        const float th = thre_s;
#pragma unroll
        for (int it = 0; it < 4; ++it) {
            int idx = (it * 256 + t) * 4;
            *(float4*)(pooledOut + b * 4096 + idx) = *(const float4*)(pooled + idx);
        }
        for (int idx = t; idx < 4096; idx += 256) {
            if (!(pooled[idx] >= th)) {
                int pos = atomicAdd(&cnt, 1);
                unsel[b * 4096 + pos] = idx;
            }
        }
        __syncthreads();
        if (t == 0) { unselN[b] = cnt; threOut[b] = th; }
    } else {
        // ---- norm + prep path ----
        __shared__ float s_part[4][64];
        const int n = blockIdx.x - 4;       // 0..255
        const int b = n >> 6;
        const int pbase = (n & 63) * 64;
        const int wv = t >> 6;              // channel group of 16
        const int l = t & 63;               // position within 64-slice
        const int sp = pbase + l;
        const float* xp = x + b * (NCH * HW) + sp;
        float xv[16];
        float ss = 0.f;
#pragma unroll
        for (int i = 0; i < 16; ++i) {
            float a = xp[(wv * 16 + i) * HW];
            xv[i] = a;
            ss += a * a;
        }
        s_part[wv][l] = ss;
        // pack bf16 and write both halves (scale=1 initially; fixup rescales unselected later)
        ushort h[16];
#pragma unroll
        for (int i = 0; i < 16; ++i) h[i] = f2bf(xv[i]);
        size_t dst1 = ((size_t)(b * 8 + wv) * 4096 + sp) * 16;
        size_t dst2 = ((size_t)(b * 8 + 4 + wv) * 4096 + sp) * 16;
        *(uint4*)(inb + dst1)     = *(const uint4*)h;
        *(uint4*)(inb + dst1 + 8) = *(const uint4*)(h + 8);
        *(uint4*)(inb + dst2)     = *(const uint4*)h;
        *(uint4*)(inb + dst2 + 8) = *(const uint4*)(h + 8);
        __syncthreads();
        if (t < 64) {
            float s = s_part[0][l] + s_part[1][l] + s_part[2][l] + s_part[3][l];
            int g = b * HW + pbase + l;
            rn[g] = 1.0f / fmaxf(sqrtf(s), 1e-8f);
            smOut[g] = 1.0f;
        }
    }
}

// ---------------- K2: qgather (bf16 hi/lo) + score init (blocks 0-3)  ||  weight prep (blocks 4-39) ----------------
__global__ void k_qgw(const float* __restrict__ x, const float* __restrict__ rn,
                      const int* __restrict__ unsel, const int* __restrict__ unselN,
                      ushort* __restrict__ qmh, ushort* __restrict__ qml, unsigned* __restrict__ scores,
                      const float* __restrict__ W, ushort* __restrict__ wbh, ushort* __restrict__ wbl) {
    const int t = threadIdx.x;
    if (blockIdx.x < 4) {
        const int b = blockIdx.x;
        const int nu = unselN[b];
        for (int qi = t; qi < nu; qi += 256) scores[b * 4096 + qi] = 0u;
        for (int idx = t; idx < nu * 64; idx += 256) {
            int qi = idx >> 6;
            int c = idx & 63;
            int q = unsel[b * 4096 + qi];
            float rq = rn[b * 4096 + q];
            float v = x[b * (NCH * HW) + c * HW + q] * rq;
            ushort hb = f2bf(v);
            size_t o = ((size_t)(b * 4096) + qi) * 64 + c;
            qmh[o] = hb;
            qml[o] = f2bf(v - bf2f(hb));
        }
    } else {
        const int u = (blockIdx.x - 4) * 256 + t;   // 0..9215 = tap*1024 + oc*16 + g
        const int tap = u >> 10;
        const int rem = u & 1023;
        const int oc = rem >> 4;
        const int g = rem & 15;
        ushort hh[8], ll[8];
#pragma unroll
        for (int j = 0; j < 8; ++j) {
            int ic = g * 8 + j;
            float v = W[(oc * 128 + ic) * 9 + tap];
            ushort hb = f2bf(v);
            hh[j] = hb;
            ll[j] = f2bf(v - bf2f(hb));
        }
        *(uint4*)(wbh + (size_t)u * 8) = *(const uint4*)hh;
        *(uint4*)(wbl + (size_t)u * 8) = *(const uint4*)ll;
    }
}

// ---------------- K3: score via MFMA — D[q,p] = q_hat . x_p, masked max over p ----------------
// grid (32 p-strips, 4 b), 256 threads = 4 waves. Strip = 128 p. M=64 q-slots per slab, K=64 ch.
// A = q_hat (hi/lo bf16), B = x bf16 (from inb grp 4-7). Same fragment pattern as k_conv_mfma.
__global__ __launch_bounds__(256, 1) void k_score(
    const ushort* __restrict__ inb, const ushort* __restrict__ qmh, const ushort* __restrict__ qml,
    const float* __restrict__ rn, const float* __restrict__ pooledM, const float* __restrict__ threArr,
    const int* __restrict__ unselN, unsigned* __restrict__ scores) {
    const int b = blockIdx.y;
    const int n0 = blockIdx.x * 128;
    const int t = threadIdx.x;
    const int lane = t & 63;
    const int wave = t >> 6;
    const int li = lane & 15;
    const int quad = lane >> 4;
    const int nu = unselN[b];

    __shared__ __align__(16) ushort s_xp[128 * 72];   // [p_local][64 c] pad 72
    __shared__ __align__(16) ushort s_qh[64 * 72];    // [q_local][64 c] pad 72
    __shared__ __align__(16) ushort s_ql[64 * 72];
    __shared__ float s_rp[128];
    __shared__ float s_neg[128];
    __shared__ unsigned s_best[64];

    // stage x tile: 128 p rows, 64 c contiguous bf16 each (from inb plain-x groups 4..7)
    for (int idx = t; idx < 1024; idx += 256) {
        int p_l = idx >> 3;
        int g = (idx >> 1) & 3;
        int sub = idx & 1;
        uint4 v = *(const uint4*)(inb + (((size_t)(b * 8 + 4 + g) * 4096) + n0 + p_l) * 16 + sub * 8);
        *(uint4*)(s_xp + p_l * 72 + g * 16 + sub * 8) = v;
    }
    if (t < 128) {
        int p = n0 + t;
        s_rp[t] = rn[b * 4096 + p];
        s_neg[t] = (pooledM[b * 4096 + p] >= threArr[b]) ? 0.0f : -INFINITY;
    }

    for (int qs0 = 0; qs0 < nu; qs0 += 64) {
        __syncthreads();   // iter0: x staging done; iter>0: prev s_best reads done
        // stage 64 q rows (hi/lo)
        for (int idx = t; idx < 512; idx += 256) {
            int q_l = idx >> 3;
            int sub = idx & 7;
            int q_g = qs0 + q_l; if (q_g > 4095) q_g = 4095;
            size_t src = ((size_t)(b * 4096) + q_g) * 64 + sub * 8;
            *(uint4*)(s_qh + q_l * 72 + sub * 8) = *(const uint4*)(qmh + src);
            *(uint4*)(s_ql + q_l * 72 + sub * 8) = *(const uint4*)(qml + src);
        }
        if (t < 64) s_best[t] = 0u;
        __syncthreads();

        // wave handles n-tiles {2*wave, 2*wave+1} (32 p), all 4 m-tiles (64 q)
        f32x4 acc[2][4];
#pragma unroll
        for (int nt = 0; nt < 2; ++nt)
#pragma unroll
            for (int mt = 0; mt < 4; ++mt) acc[nt][mt] = (f32x4){0.f, 0.f, 0.f, 0.f};
#pragma unroll
        for (int k0 = 0; k0 < 2; ++k0) {
            short8 b0 = *(const short8*)(s_xp + ((size_t)((2 * wave) * 16 + li)) * 72 + k0 * 32 + quad * 8);
            short8 b1 = *(const short8*)(s_xp + ((size_t)((2 * wave + 1) * 16 + li)) * 72 + k0 * 32 + quad * 8);
#pragma unroll
            for (int mt = 0; mt < 4; ++mt) {
                short8 ah = *(const short8*)(s_qh + ((size_t)(mt * 16 + li)) * 72 + k0 * 32 + quad * 8);
                short8 al = *(const short8*)(s_ql + ((size_t)(mt * 16 + li)) * 72 + k0 * 32 + quad * 8);
                acc[0][mt] = __builtin_amdgcn_mfma_f32_16x16x32_bf16(ah, b0, acc[0][mt], 0, 0, 0);
                acc[0][mt] = __builtin_amdgcn_mfma_f32_16x16x32_bf16(al, b0, acc[0][mt], 0, 0, 0);
                acc[1][mt] = __builtin_amdgcn_mfma_f32_16x16x32_bf16(ah, b1, acc[1][mt], 0, 0, 0);
                acc[1][mt] = __builtin_amdgcn_mfma_f32_16x16x32_bf16(al, b1, acc[1][mt], 0, 0, 0);
            }
        }
        // epilogue: mask + scale, reduce max over the 16 p-lanes, scoreboard per q
        const float rp0 = s_rp[(2 * wave) * 16 + li];
        const float ng0 = s_neg[(2 * wave) * 16 + li];
        const float rp1 = s_rp[(2 * wave + 1) * 16 + li];
        const float ng1 = s_neg[(2 * wave + 1) * 16 + li];
#pragma unroll
        for (int mt = 0; mt < 4; ++mt) {
#pragma unroll
            for (int r = 0; r < 4; ++r) {
                float sc = fmaxf(acc[0][mt][r] * rp0 + ng0, acc[1][mt][r] * rp1 + ng1);
                sc = fmaxf(sc, __shfl_xor(sc, 1));
                sc = fmaxf(sc, __shfl_xor(sc, 2));
                sc = fmaxf(sc, __shfl_xor(sc, 4));
                sc = fmaxf(sc, __shfl_xor(sc, 8));
                if (li == 0) atomicMax(&s_best[mt * 16 + quad * 4 + r], mapf(sc));
            }
        }
        __syncthreads();
        if (t < 64 && qs0 + t < nu) atomicMax(scores + b * 4096 + qs0 + t, s_best[t]);
    }
}

// ---------------- K4: fixup — finalize sm for unselected q, rescale their inb entries ----------------
__global__ void k_fixup(const float* __restrict__ x, const int* __restrict__ unsel,
                        const int* __restrict__ unselN, const unsigned* __restrict__ scores,
                        float* __restrict__ smOut, ushort* __restrict__ inb) {
    const int b = blockIdx.x;
    const int t = threadIdx.x;
    const int nu = unselN[b];
    __shared__ float s_sm[4096];
    for (int qi = t; qi < nu; qi += 256) {
        float sm = unmapf(scores[b * 4096 + qi]) * 0.5f + 0.5f;
        s_sm[qi] = sm;
        smOut[b * 4096 + unsel[b * 4096 + qi]] = sm;
    }
    __syncthreads();
    for (int idx = t; idx < nu * 64; idx += 256) {
        int qi = idx >> 6;
        int c = idx & 63;
        int q = unsel[b * 4096 + qi];
        float v = x[b * (NCH * HW) + c * HW + q] * s_sm[qi];
        inb[(((size_t)(b * 8 + (c >> 4)) * 4096) + q) * 16 + (c & 15)] = f2bf(v);
    }
}

// ---------------- K5: MFMA implicit-GEMM conv 3x3 (128->64) + bias + GN partials ----------------
// grid (16 rowblk, 4 ocblk, 4 b), block 256 = 4 waves (one per output row).
// Wave computes 16 oc x 64 w via 4 C-tiles of 16x16. A = weights (m=oc), B = input (n=w).
__global__ __launch_bounds__(256) void k_conv_mfma(
    const ushort* __restrict__ inb, const ushort* __restrict__ wbh, const ushort* __restrict__ wbl,
    const float* __restrict__ bfuse, float* __restrict__ y,
    float* __restrict__ gnS1, float* __restrict__ gnS2) {
    const int rowblk = blockIdx.x;
    const int ocblk = blockIdx.y;
    const int b = blockIdx.z;
    const int t = threadIdx.x;
    const int lane = t & 63;
    const int wave = t >> 6;
    const int li = lane & 15;
    const int quad = lane >> 4;
    const int h0 = rowblk * 4;
    const int oc0 = ocblk * 16;

    __shared__ __align__(16) ushort s_in[6 * 66 * 40];   // [r][c][32ic pad40] halves
    __shared__ __align__(16) ushort s_wh[9 * 16 * 40];   // [tap][oc][32ic pad40]
    __shared__ __align__(16) ushort s_wl[9 * 16 * 40];
    __shared__ float red1[256];
    __shared__ float red2[256];

    f32x4 acc[4];
#pragma unroll
    for (int j = 0; j < 4; ++j) acc[j] = (f32x4){0.f, 0.f, 0.f, 0.f};

    for (int chunk = 0; chunk < 4; ++chunk) {
        __syncthreads();
        // stage input slab: rows h0-1..h0+4, cols -1..64, 32 ic (4 x 16B parts per cell)
        // inb layout: [b][8 grp][sp][16 halves]; chunk c covers grps {2c, 2c+1}
        for (int idx = t; idx < 1584; idx += 256) {
            int part = idx & 3;
            int cell = idx >> 2;
            int r = cell / 66;
            int c = cell - r * 66;
            int h = h0 + r - 1;
            int w = c - 1;
            uint4 v = make_uint4(0u, 0u, 0u, 0u);
            if ((unsigned)h < 64u && (unsigned)w < 64u) {
                int grp = 2 * chunk + (part >> 1);
                int sub = part & 1;
                v = *(const uint4*)(inb + (((size_t)(b * 8 + grp) * 4096 + h * 64 + w) * 16 + sub * 8));
            }
            *(uint4*)(s_in + (size_t)cell * 40 + part * 8) = v;
        }
        // stage weights: {hi,lo} x 9 taps x 16 oc x 4 parts
        const int ic0 = chunk * 32;
        for (int idx = t; idx < 1152; idx += 256) {
            int part = idx & 3;
            int uu = idx >> 2;              // hl*144 + tap*16 + o
            int hl = uu / 144;
            int rem = uu - hl * 144;
            int tap = rem >> 4;
            int o = rem & 15;
            const ushort* src = (hl ? wbl : wbh) + ((size_t)(tap * 64 + oc0 + o) * 128 + ic0 + part * 8);
            uint4 v = *(const uint4*)src;
            ushort* dst = (hl ? s_wl : s_wh) + ((size_t)(tap * 16 + o) * 40 + part * 8);
            *(uint4*)dst = v;
        }
        __syncthreads();
#pragma unroll
        for (int kh = 0; kh < 3; ++kh) {
            const int r = wave + kh;
#pragma unroll
            for (int kw = 0; kw < 3; ++kw) {
                const int tap = kh * 3 + kw;
                short8 ah = *(const short8*)(s_wh + (size_t)(tap * 16 + li) * 40 + quad * 8);
                short8 al = *(const short8*)(s_wl + (size_t)(tap * 16 + li) * 40 + quad * 8);
#pragma unroll
                for (int j = 0; j < 4; ++j) {
                    int c = j * 16 + li + kw;
                    short8 bv = *(const short8*)(s_in + ((size_t)(r * 66 + c) * 40 + quad * 8));
                    acc[j] = __builtin_amdgcn_mfma_f32_16x16x32_bf16(ah, bv, acc[j], 0, 0, 0);
                    acc[j] = __builtin_amdgcn_mfma_f32_16x16x32_bf16(al, bv, acc[j], 0, 0, 0);
                }
            }
        }
    }
    // epilogue: bias, store (coalesced: col=lane&15 is w), GN partial sums
    float bias[4];
#pragma unroll
    for (int reg = 0; reg < 4; ++reg) bias[reg] = bfuse[oc0 + quad * 4 + reg];
    float s1 = 0.f, s2 = 0.f;
    const int hrow = h0 + wave;
#pragma unroll
    for (int j = 0; j < 4; ++j) {
#pragma unroll
        for (int reg = 0; reg < 4; ++reg) {
            float v = acc[j][reg] + bias[reg];
            y[((size_t)(b * 64 + oc0 + quad * 4 + reg)) * HW + hrow * 64 + j * 16 + li] = v;
            s1 += v; s2 += v * v;
        }
    }
    red1[t] = s1; red2[t] = s2;
    __syncthreads();
    for (int s = 128; s > 0; s >>= 1) {
        if (t < s) { red1[t] += red1[t + s]; red2[t] += red2[t + s]; }
        __syncthreads();
    }
    if (t == 0) {
        atomicAdd(&gnS1[b], red1[0]);
        atomicAdd(&gnS2[b], red2[0]);
    }
}

// ---------------- K6: GroupNorm(1 group) + affine + ReLU, in-place on out ----------------
__global__ void k_gn(float* __restrict__ out, const float* __restrict__ gnS1, const float* __restrict__ gnS2,
                     const float* __restrict__ gamma, const float* __restrict__ beta) {
    const int e = (blockIdx.x * 256 + threadIdx.x) * 4;
    const int b = e >> 18;
    const int c = (e >> 12) & 63;
    const float inv = 1.0f / 262144.0f;
    float mu = gnS1[b] * inv;
    float var = gnS2[b] * inv - mu * mu;
    float rs = rsqrtf(var + 1e-5f);
    float scale = rs * gamma[c];
    float shift = beta[c] - mu * scale;
    float4 v = *(const float4*)(out + e);
    float4 o;
    o.x = fmaxf(v.x * scale + shift, 0.0f);
    o.y = fmaxf(v.y * scale + shift, 0.0f);
    o.z = fmaxf(v.z * scale + shift, 0.0f);
    o.w = fmaxf(v.w * scale + shift, 0.0f);
    *(float4*)(out + e) = o;
}

extern "C" void kernel_launch(void* const* d_in, const int* in_sizes, int n_in,
                              void* d_out, int out_size, void* d_ws, size_t ws_size,
                              hipStream_t stream) {
    const float* fdm   = (const float*)d_in[0];
    const float* x     = (const float*)d_in[1];
    const float* Wf    = (const float*)d_in[2];
    const float* bfuse = (const float*)d_in[3];
    const float* gamma = (const float*)d_in[4];
    const float* beta  = (const float*)d_in[5];
    float* out = (float*)d_out;
    float* ws  = (float*)d_ws;

    // workspace layout (float offsets, all 16B-aligned)
    float*    rn      = ws;                         // 16384
    float*    pooledM = rn + 16384;                 // 16384
    int*      unsel   = (int*)(pooledM + 16384);    // 16384
    unsigned* scores  = (unsigned*)(unsel + 16384); // 16384
    float*    thre    = (float*)(scores + 16384);   // 4
    int*      unselN  = (int*)(thre + 4);           // 4
    float*    gnS1    = (float*)(unselN + 4);       // 4
    float*    gnS2    = gnS1 + 4;                   // 4
    ushort*   wbh     = (ushort*)(gnS2 + 4);        // 73728 halves
    ushort*   wbl     = wbh + 73728;                // 73728 halves
    ushort*   qmh     = wbl + 73728;                // 1048576 halves (4*4096*64)
    ushort*   qml     = qmh + 1048576;              // 1048576 halves
    ushort*   inb     = qml + 1048576;              // 4194304 halves (8 MB)

    float* yout  = out;                             // conv output in out[0..1M), GN in-place
    float* smOut = out + 1048576;                   // second output

    k_pnp<<<dim3(260), dim3(256), 0, stream>>>(fdm, x, pooledM, thre, unsel, unselN,
                                               gnS1, gnS2, rn, smOut, inb);
    k_qgw<<<dim3(40), dim3(256), 0, stream>>>(x, rn, unsel, unselN, qmh, qml, scores, Wf, wbh, wbl);
    k_score<<<dim3(32, 4), dim3(256), 0, stream>>>(inb, qmh, qml, rn, pooledM, thre, unselN, scores);
    k_fixup<<<dim3(4), dim3(256), 0, stream>>>(x, unsel, unselN, scores, smOut, inb);
    k_conv_mfma<<<dim3(16, 4, 4), dim3(256), 0, stream>>>(inb, wbh, wbl, bfuse, yout, gnS1, gnS2);
    k_gn<<<dim3(1024), dim3(256), 0, stream>>>(yout, gnS1, gnS2, gamma, beta);
}

// Round 7
// 114.355 us; speedup vs baseline: 1.3507x; 1.0563x over previous
//
#include <hip/hip_runtime.h>
#include <math.h>

// Problem constants: b=4, f=64, h=w=64, HW=4096
// Inputs: fdm [4,1,128,128], x [4,64,64,64], W_fuse [64,128,3,3], b_fuse [64], gamma [64], beta [64]
// Outputs concatenated: x0 [4,64,64,64] (1048576 f32) then sm [4,1,64,64] (16384 f32)

#define HW 4096
#define NCH 64

typedef __attribute__((ext_vector_type(8))) short short8;
typedef __attribute__((ext_vector_type(4))) float f32x4;

static __device__ __forceinline__ ushort f2bf(float f) {
    unsigned u = __float_as_uint(f);
    unsigned r = (u + 0x7fffu + ((u >> 16) & 1u)) >> 16;   // RNE
    return (ushort)r;
}
static __device__ __forceinline__ float bf2f(ushort h) {
    return __uint_as_float(((unsigned)h) << 16);
}
// order-preserving float <-> uint map for atomicMax
static __device__ __forceinline__ unsigned mapf(float f) {
    unsigned u = __float_as_uint(f);
    return u ^ ((unsigned)((int)u >> 31) | 0x80000000u);
}
static __device__ __forceinline__ float unmapf(unsigned u) {
    unsigned b = (u & 0x80000000u) ? (u ^ 0x80000000u) : ~u;
    return __uint_as_float(b);
}

// ---------------- K1: pool (blk 0-3) || norm+bf16-prep (blk 4-259) || weight-prep (blk 260-295) ----------------
// inb layout: [b][8 grp][sp 4096][16 halves]; grp 0-3 = sm*x ch {0..63}, grp 4-7 = x ch {0..63}.
// Both halves written with scale=1; conv rescales the ~50 unselected cells in LDS.
__global__ __launch_bounds__(256) void k_pnp(
    const float* __restrict__ fdm, const float* __restrict__ x, const float* __restrict__ W,
    float* __restrict__ pooledOut, float* __restrict__ threOut,
    int* __restrict__ unsel, int* __restrict__ unselN, unsigned* __restrict__ scores,
    float* __restrict__ gnS1, float* __restrict__ gnS2,
    float* __restrict__ rn, float* __restrict__ smOut, ushort* __restrict__ inb,
    ushort* __restrict__ wbh, ushort* __restrict__ wbl) {
    const int t = threadIdx.x;
    if (blockIdx.x < 4) {
        // ---- pool path ----
        const int b = blockIdx.x;
        __shared__ float pooled[4096];
        __shared__ float red[256];
        __shared__ int cnt;
        const float* fb = fdm + b * 16384;
        float lmax = -1.0f;
#pragma unroll
        for (int it = 0; it < 8; ++it) {
            int id2 = it * 256 + t;
            int i = id2 >> 5;
            int j2 = id2 & 31;
            const float* base = fb + i * 256 + j2 * 4;
            float4 a = *(const float4*)base;
            float4 c = *(const float4*)(base + 128);
            float p0 = fmaxf(fmaxf(a.x, a.y), fmaxf(c.x, c.y));
            float p1 = fmaxf(fmaxf(a.z, a.w), fmaxf(c.z, c.w));
            pooled[i * 64 + j2 * 2]     = p0;
            pooled[i * 64 + j2 * 2 + 1] = p1;
            lmax = fmaxf(lmax, fmaxf(p0, p1));
        }
        red[t] = lmax;
        __syncthreads();
        for (int s = 128; s > 0; s >>= 1) {
            if (t < s) red[t] = fmaxf(red[t], red[t + s]);
            __syncthreads();
        }
        __shared__ float thre_s;
        if (t == 0) {
            thre_s = fminf(0.5f, red[0] / 3.0f);   // exact reference fp32 rounding
            cnt = 0;
            gnS1[b] = 0.0f; gnS2[b] = 0.0f;
        }
        __syncthreads();
        const float th = thre_s;
#pragma unroll
        for (int it = 0; it < 4; ++it) {
            int idx = (it * 256 + t) * 4;
            *(float4*)(pooledOut + b * 4096 + idx) = *(const float4*)(pooled + idx);
        }
        for (int idx = t; idx < 4096; idx += 256) {
            scores[b * 4096 + idx] = 0u;           // zero-init scoreboard (ws is poisoned)
            if (!(pooled[idx] >= th)) {
                int pos = atomicAdd(&cnt, 1);
                unsel[b * 4096 + pos] = idx;
            }
        }
        __syncthreads();
        if (t == 0) { unselN[b] = cnt; threOut[b] = th; }
    } else if (blockIdx.x < 260) {
        // ---- norm + prep path ----
        __shared__ float s_part[4][64];
        const int n = blockIdx.x - 4;       // 0..255
        const int b = n >> 6;
        const int pbase = (n & 63) * 64;
        const int wv = t >> 6;              // channel group of 16
        const int l = t & 63;               // position within 64-slice
        const int sp = pbase + l;
        const float* xp = x + b * (NCH * HW) + sp;
        float xv[16];
        float ss = 0.f;
#pragma unroll
        for (int i = 0; i < 16; ++i) {
            float a = xp[(wv * 16 + i) * HW];
            xv[i] = a;
            ss += a * a;
        }
        s_part[wv][l] = ss;
        ushort h[16];
#pragma unroll
        for (int i = 0; i < 16; ++i) h[i] = f2bf(xv[i]);
        size_t dst1 = ((size_t)(b * 8 + wv) * 4096 + sp) * 16;
        size_t dst2 = ((size_t)(b * 8 + 4 + wv) * 4096 + sp) * 16;
        *(uint4*)(inb + dst1)     = *(const uint4*)h;
        *(uint4*)(inb + dst1 + 8) = *(const uint4*)(h + 8);
        *(uint4*)(inb + dst2)     = *(const uint4*)h;
        *(uint4*)(inb + dst2 + 8) = *(const uint4*)(h + 8);
        __syncthreads();
        if (t < 64) {
            float s = s_part[0][l] + s_part[1][l] + s_part[2][l] + s_part[3][l];
            int g = b * HW + pbase + l;
            rn[g] = 1.0f / fmaxf(sqrtf(s), 1e-8f);
            smOut[g] = 1.0f;
        }
    } else {
        // ---- weight prep: bf16 hi/lo, layout [tap][oc][ic128] ----
        const int u = (blockIdx.x - 260) * 256 + t;   // 0..9215 = tap*1024 + oc*16 + g
        const int tap = u >> 10;
        const int rem = u & 1023;
        const int oc = rem >> 4;
        const int g = rem & 15;
        ushort hh[8], ll[8];
#pragma unroll
        for (int j = 0; j < 8; ++j) {
            int ic = g * 8 + j;
            float v = W[(oc * 128 + ic) * 9 + tap];
            ushort hb = f2bf(v);
            hh[j] = hb;
            ll[j] = f2bf(v - bf2f(hb));
        }
        *(uint4*)(wbh + (size_t)u * 8) = *(const uint4*)hh;
        *(uint4*)(wbl + (size_t)u * 8) = *(const uint4*)ll;
    }
}

// ---------------- K2: score via MFMA — D[q,p] = q_hat . x_p, masked max over p ----------------
// grid (32 p-strips, 4 b), 256 threads = 4 waves. Strip = 128 p, wave covers 32 p (2 n-tiles).
// A = q_hat hi/lo gathered into LDS from x (rq prefolded); B = x bf16 read DIRECTLY from inb (global).
__global__ __launch_bounds__(256) void k_score(
    const float* __restrict__ x, const float* __restrict__ rn,
    const float* __restrict__ pooledM, const float* __restrict__ threArr,
    const int* __restrict__ unsel, const int* __restrict__ unselN,
    const ushort* __restrict__ inb, unsigned* __restrict__ scores) {
    const int b = blockIdx.y;
    const int n0 = blockIdx.x * 128;
    const int t = threadIdx.x;
    const int lane = t & 63;
    const int wave = t >> 6;
    const int li = lane & 15;
    const int quad = lane >> 4;
    const int nu = unselN[b];
    if (nu == 0) return;

    __shared__ __align__(16) ushort s_qh[64 * 72];    // [q_local][64 c] pad 72
    __shared__ __align__(16) ushort s_ql[64 * 72];
    __shared__ unsigned s_best[64];

    const float th = threArr[b];
    const int p0 = n0 + (2 * wave) * 16 + li;
    const int p1 = n0 + (2 * wave + 1) * 16 + li;
    const float rp0 = rn[b * 4096 + p0];
    const float rp1 = rn[b * 4096 + p1];
    const float ng0 = (pooledM[b * 4096 + p0] >= th) ? 0.0f : -INFINITY;
    const float ng1 = (pooledM[b * 4096 + p1] >= th) ? 0.0f : -INFINITY;

    for (int qs0 = 0; qs0 < nu; qs0 += 64) {
        __syncthreads();   // iter>0: prior s_best reads done
        // gather 64 q rows (hi/lo) from x, rq prefolded; zero-pad beyond nu
        for (int idx = t; idx < 4096; idx += 256) {
            int q_l = idx >> 6;
            int c = idx & 63;
            int qg = qs0 + q_l;
            float v = 0.0f;
            if (qg < nu) {
                int q = unsel[b * 4096 + qg];
                v = x[b * (NCH * HW) + c * HW + q] * rn[b * 4096 + q];
            }
            ushort hb = f2bf(v);
            s_qh[q_l * 72 + c] = hb;
            s_ql[q_l * 72 + c] = f2bf(v - bf2f(hb));
        }
        if (t < 64) s_best[t] = 0u;
        __syncthreads();

        f32x4 acc[2][4];
#pragma unroll
        for (int nt = 0; nt < 2; ++nt)
#pragma unroll
            for (int mt = 0; mt < 4; ++mt) acc[nt][mt] = (f32x4){0.f, 0.f, 0.f, 0.f};
#pragma unroll
        for (int k0 = 0; k0 < 2; ++k0) {
            const int cb = k0 * 32 + quad * 8;
            const int grp = 4 + (cb >> 4);
            const int sub = cb & 15;
            short8 b0 = *(const short8*)(inb + (((size_t)(b * 8 + grp) * 4096) + p0) * 16 + sub);
            short8 b1 = *(const short8*)(inb + (((size_t)(b * 8 + grp) * 4096) + p1) * 16 + sub);
#pragma unroll
            for (int mt = 0; mt < 4; ++mt) {
                short8 ah = *(const short8*)(s_qh + (size_t)(mt * 16 + li) * 72 + cb);
                short8 al = *(const short8*)(s_ql + (size_t)(mt * 16 + li) * 72 + cb);
                acc[0][mt] = __builtin_amdgcn_mfma_f32_16x16x32_bf16(ah, b0, acc[0][mt], 0, 0, 0);
                acc[0][mt] = __builtin_amdgcn_mfma_f32_16x16x32_bf16(al, b0, acc[0][mt], 0, 0, 0);
                acc[1][mt] = __builtin_amdgcn_mfma_f32_16x16x32_bf16(ah, b1, acc[1][mt], 0, 0, 0);
                acc[1][mt] = __builtin_amdgcn_mfma_f32_16x16x32_bf16(al, b1, acc[1][mt], 0, 0, 0);
            }
        }
        // epilogue: mask + scale, reduce max over the 16 p-lanes, scoreboard per q
#pragma unroll
        for (int mt = 0; mt < 4; ++mt) {
#pragma unroll
            for (int r = 0; r < 4; ++r) {
                float sc = fmaxf(acc[0][mt][r] * rp0 + ng0, acc[1][mt][r] * rp1 + ng1);
                sc = fmaxf(sc, __shfl_xor(sc, 1));
                sc = fmaxf(sc, __shfl_xor(sc, 2));
                sc = fmaxf(sc, __shfl_xor(sc, 4));
                sc = fmaxf(sc, __shfl_xor(sc, 8));
                if (li == 0) atomicMax(&s_best[mt * 16 + quad * 4 + r], mapf(sc));
            }
        }
        __syncthreads();
        if (t < 64 && qs0 + t < nu) atomicMax(scores + b * 4096 + qs0 + t, s_best[t]);
    }
}

// ---------------- K3: MFMA implicit-GEMM conv 3x3 (128->64) + in-LDS sm fixup + bias + GN partials ----------------
// grid (16 rowblk, 4 ocblk, 4 b), block 256 = 4 waves (one per output row).
// Wave computes 16 oc x 64 w via 4 C-tiles of 16x16. A = weights (m=oc), B = input (n=w).
__global__ __launch_bounds__(256) void k_conv_mfma(
    const ushort* __restrict__ inb, const ushort* __restrict__ wbh, const ushort* __restrict__ wbl,
    const float* __restrict__ bfuse, const int* __restrict__ unsel, const int* __restrict__ unselN,
    const unsigned* __restrict__ scores, float* __restrict__ smOut,
    float* __restrict__ y, float* __restrict__ gnS1, float* __restrict__ gnS2) {
    const int rowblk = blockIdx.x;
    const int ocblk = blockIdx.y;
    const int b = blockIdx.z;
    const int t = threadIdx.x;
    const int lane = t & 63;
    const int wave = t >> 6;
    const int li = lane & 15;
    const int quad = lane >> 4;
    const int h0 = rowblk * 4;
    const int oc0 = ocblk * 16;
    const int nu = unselN[b];

    __shared__ __align__(16) ushort s_in[6 * 66 * 40];   // [r][c][32ic pad40] halves
    __shared__ __align__(16) ushort s_wh[9 * 16 * 40];   // [tap][oc][32ic pad40]
    __shared__ __align__(16) ushort s_wl[9 * 16 * 40];
    __shared__ float red1[256];
    __shared__ float red2[256];

    // designated block per batch finalizes the sm output for unselected q
    if (rowblk == 0 && ocblk == 0) {
        for (int qi = t; qi < nu; qi += 256) {
            float sm = unmapf(scores[b * 4096 + qi]) * 0.5f + 0.5f;
            smOut[b * 4096 + unsel[b * 4096 + qi]] = sm;
        }
    }

    f32x4 acc[4];
#pragma unroll
    for (int j = 0; j < 4; ++j) acc[j] = (f32x4){0.f, 0.f, 0.f, 0.f};

    for (int chunk = 0; chunk < 4; ++chunk) {
        __syncthreads();
        // stage input slab: rows h0-1..h0+4, cols -1..64, 32 ic (4 x 16B parts per cell)
        // inb layout: [b][8 grp][sp][16 halves]; chunk c covers grps {2c, 2c+1}
        for (int idx = t; idx < 1584; idx += 256) {
            int part = idx & 3;
            int cell = idx >> 2;
            int r = cell / 66;
            int c = cell - r * 66;
            int h = h0 + r - 1;
            int w = c - 1;
            uint4 v = make_uint4(0u, 0u, 0u, 0u);
            if ((unsigned)h < 64u && (unsigned)w < 64u) {
                int grp = 2 * chunk + (part >> 1);
                int sub = part & 1;
                v = *(const uint4*)(inb + (((size_t)(b * 8 + grp) * 4096 + h * 64 + w) * 16 + sub * 8));
            }
            *(uint4*)(s_in + (size_t)cell * 40 + part * 8) = v;
        }
        // stage weights: {hi,lo} x 9 taps x 16 oc x 4 parts
        const int ic0 = chunk * 32;
        for (int idx = t; idx < 1152; idx += 256) {
            int part = idx & 3;
            int uu = idx >> 2;              // hl*144 + tap*16 + o
            int hl = uu / 144;
            int rem = uu - hl * 144;
            int tap = rem >> 4;
            int o = rem & 15;
            const ushort* src = (hl ? wbl : wbh) + ((size_t)(tap * 64 + oc0 + o) * 128 + ic0 + part * 8);
            uint4 v = *(const uint4*)src;
            ushort* dst = (hl ? s_wl : s_wh) + ((size_t)(tap * 16 + o) * 40 + part * 8);
            *(uint4*)dst = v;
        }
        // in-LDS sm rescale of unselected positions (scaled half = chunks 0,1 only)
        if (chunk < 2) {
            __syncthreads();   // staging visible before modification
            for (int idx = t; idx < nu * 4; idx += 256) {
                int qi = idx >> 2;
                int part = idx & 3;
                int q = unsel[b * 4096 + qi];
                int hq = q >> 6, wq = q & 63;
                int r = hq - h0 + 1;
                if ((unsigned)r < 6u) {
                    float sm = unmapf(scores[b * 4096 + qi]) * 0.5f + 0.5f;
                    ushort* ptr = s_in + (size_t)(r * 66 + wq + 1) * 40 + part * 8;
                    ushort hv[8];
                    *(uint4*)hv = *(const uint4*)ptr;
#pragma unroll
                    for (int j = 0; j < 8; ++j) hv[j] = f2bf(bf2f(hv[j]) * sm);
                    *(uint4*)ptr = *(const uint4*)hv;
                }
            }
        }
        __syncthreads();
#pragma unroll
        for (int kh = 0; kh < 3; ++kh) {
            const int r = wave + kh;
#pragma unroll
            for (int kw = 0; kw < 3; ++kw) {
                const int tap = kh * 3 + kw;
                short8 ah = *(const short8*)(s_wh + (size_t)(tap * 16 + li) * 40 + quad * 8);
                short8 al = *(const short8*)(s_wl + (size_t)(tap * 16 + li) * 40 + quad * 8);
#pragma unroll
                for (int j = 0; j < 4; ++j) {
                    int c = j * 16 + li + kw;
                    short8 bv = *(const short8*)(s_in + ((size_t)(r * 66 + c) * 40 + quad * 8));
                    acc[j] = __builtin_amdgcn_mfma_f32_16x16x32_bf16(ah, bv, acc[j], 0, 0, 0);
                    acc[j] = __builtin_amdgcn_mfma_f32_16x16x32_bf16(al, bv, acc[j], 0, 0, 0);
                }
            }
        }
    }
    // epilogue: bias, store (coalesced: col=lane&15 is w), GN partial sums
    float bias[4];
#pragma unroll
    for (int reg = 0; reg < 4; ++reg) bias[reg] = bfuse[oc0 + quad * 4 + reg];
    float s1 = 0.f, s2 = 0.f;
    const int hrow = h0 + wave;
#pragma unroll
    for (int j = 0; j < 4; ++j) {
#pragma unroll
        for (int reg = 0; reg < 4; ++reg) {
            float v = acc[j][reg] + bias[reg];
            y[((size_t)(b * 64 + oc0 + quad * 4 + reg)) * HW + hrow * 64 + j * 16 + li] = v;
            s1 += v; s2 += v * v;
        }
    }
    red1[t] = s1; red2[t] = s2;
    __syncthreads();
    for (int s = 128; s > 0; s >>= 1) {
        if (t < s) { red1[t] += red1[t + s]; red2[t] += red2[t + s]; }
        __syncthreads();
    }
    if (t == 0) {
        atomicAdd(&gnS1[b], red1[0]);
        atomicAdd(&gnS2[b], red2[0]);
    }
}

// ---------------- K4: GroupNorm(1 group) + affine + ReLU, in-place on out ----------------
__global__ void k_gn(float* __restrict__ out, const float* __restrict__ gnS1, const float* __restrict__ gnS2,
                     const float* __restrict__ gamma, const float* __restrict__ beta) {
    const int e = (blockIdx.x * 256 + threadIdx.x) * 4;
    const int b = e >> 18;
    const int c = (e >> 12) & 63;
    const float inv = 1.0f / 262144.0f;
    float mu = gnS1[b] * inv;
    float var = gnS2[b] * inv - mu * mu;
    float rs = rsqrtf(var + 1e-5f);
    float scale = rs * gamma[c];
    float shift = beta[c] - mu * scale;
    float4 v = *(const float4*)(out + e);
    float4 o;
    o.x = fmaxf(v.x * scale + shift, 0.0f);
    o.y = fmaxf(v.y * scale + shift, 0.0f);
    o.z = fmaxf(v.z * scale + shift, 0.0f);
    o.w = fmaxf(v.w * scale + shift, 0.0f);
    *(float4*)(out + e) = o;
}

extern "C" void kernel_launch(void* const* d_in, const int* in_sizes, int n_in,
                              void* d_out, int out_size, void* d_ws, size_t ws_size,
                              hipStream_t stream) {
    const float* fdm   = (const float*)d_in[0];
    const float* x     = (const float*)d_in[1];
    const float* Wf    = (const float*)d_in[2];
    const float* bfuse = (const float*)d_in[3];
    const float* gamma = (const float*)d_in[4];
    const float* beta  = (const float*)d_in[5];
    float* out = (float*)d_out;
    float* ws  = (float*)d_ws;

    // workspace layout (float offsets, all 16B-aligned)
    float*    rn      = ws;                         // 16384
    float*    pooledM = rn + 16384;                 // 16384
    int*      unsel   = (int*)(pooledM + 16384);    // 16384
    unsigned* scores  = (unsigned*)(unsel + 16384); // 16384
    float*    thre    = (float*)(scores + 16384);   // 4
    int*      unselN  = (int*)(thre + 4);           // 4
    float*    gnS1    = (float*)(unselN + 4);       // 4
    float*    gnS2    = gnS1 + 4;                   // 4
    ushort*   wbh     = (ushort*)(gnS2 + 4);        // 73728 halves
    ushort*   wbl     = wbh + 73728;                // 73728 halves
    ushort*   inb     = wbl + 73728;                // 4194304 halves (8 MB)

    float* yout  = out;                             // conv output in out[0..1M), GN in-place
    float* smOut = out + 1048576;                   // second output

    k_pnp<<<dim3(296), dim3(256), 0, stream>>>(fdm, x, Wf, pooledM, thre, unsel, unselN,
                                               scores, gnS1, gnS2, rn, smOut, inb, wbh, wbl);
    k_score<<<dim3(32, 4), dim3(256), 0, stream>>>(x, rn, pooledM, thre, unsel, unselN, inb, scores);
    k_conv_mfma<<<dim3(16, 4, 4), dim3(256), 0, stream>>>(inb, wbh, wbl, bfuse, unsel, unselN,
                                                          scores, smOut, yout, gnS1, gnS2);
    k_gn<<<dim3(1024), dim3(256), 0, stream>>>(yout, gnS1, gnS2, gamma, beta);
}